// Round 12
// baseline (1065.751 us; speedup 1.0000x reference)
//
#include <hip/hip_runtime.h>
#include <hip/hip_bf16.h>

// Sumformer inner block -- R12: 128-node fused chains, 32x32x16 MFMA,
// k8-slab ring-3 weight staging with counted vmcnt + setprio.
// R11 post-mortem: global-streamed weights are L2-BW-bound (453MB HBM-side
// traffic/dispatch); weights must stage through LDS once per block (R9).
// R9's limiter: effective LDS BW ~34 B/cy from lockstep + 8x act-tile dup.
// R12 cuts LDS bytes/FLOP 24% (128 nodes amortize weight reads) and uses
// {stage; vmcnt(1); barrier; ds_read; lgkm0; barrier; stage; setprio MFMA}
// per k16 step -- one slab always in flight, never drain-0 mid-loop.
// Layouts: A/B frag row/col = lane&31, k = 8*(lane>>5)+e (extends verified
// 16x16x32 pattern); C/D col=lane&31, row=(reg&3)+8*(reg>>2)+4*(lane>>5)
// [m74/m101-verified]. Weight slab s = k-range [8s,8s+8): granule p holds
// W[8s..8s+7][p]; ring slot s%3, LDS addr = slot*8192 + p*16 (linear stage,
// sequential-lane reads).

typedef __attribute__((ext_vector_type(8)))  short bf16x8;
typedef __attribute__((ext_vector_type(4)))  float f32x4;
typedef __attribute__((ext_vector_type(16))) float f32x16;

#define N_NODES 131072
#define NUM_G   1024

__device__ __forceinline__ float lrelu_f(float v) { return v >= 0.f ? v : 0.01f * v; }
__device__ __forceinline__ short f2bs(float f) {
  union { __hip_bfloat16 h; short s; } q; q.h = __float2bfloat16(f); return q.s;
}
__device__ __forceinline__ float bs2f(unsigned short u) {
  unsigned x = ((unsigned)u) << 16; return __uint_as_float(x);
}
__device__ __forceinline__ void gll16(const __hip_bfloat16* g, char* l) {
  __builtin_amdgcn_global_load_lds((const __attribute__((address_space(1))) void*)g,
                                   (__attribute__((address_space(3))) void*)l, 16, 0, 0);
}

__global__ void sentinel(float* out, float v) {
  if (blockIdx.x == 0 && threadIdx.x == 0) out[0] = v;
}

// Old layout (for gemm_mfma only): WT[p][k] = bf16(W[k][p])
__global__ void wt_conv(const float* __restrict__ W, __hip_bfloat16* __restrict__ WT, int K, int P) {
  __shared__ float tile[32][33];
  const int p0 = blockIdx.x << 5, k0 = blockIdx.y << 5;
  const int tx = threadIdx.x & 31, ty = threadIdx.x >> 5;
#pragma unroll
  for (int i = 0; i < 4; ++i) {
    int r = ty + (i << 3);
    tile[r][tx] = W[(size_t)(k0 + r) * P + p0 + tx];
  }
  __syncthreads();
#pragma unroll
  for (int i = 0; i < 4; ++i) {
    int r = ty + (i << 3);
    WT[(size_t)(p0 + r) * K + k0 + tx] = __float2bfloat16(tile[tx][r]);
  }
}

// Slab-granule layout: granule (k>>3)*P + p holds W[8*(k>>3)..+7][p] bf16x8.
template<int SHIFT>   // SHIFT = log2(P)
__global__ void wt_convC(const float* __restrict__ W, __hip_bfloat16* __restrict__ WTc) {
  int idx = blockIdx.x * 256 + threadIdx.x;
  int p = idx & ((1 << SHIFT) - 1);
  int k = idx >> SHIFT;
  WTc[((size_t)((k >> 3) << SHIFT) + p) * 8 + (k & 7)] = __float2bfloat16(W[idx]);
}

__global__ void sigma_fin(const float* __restrict__ sums,
                          const int* __restrict__ ids,
                          __hip_bfloat16* __restrict__ sigma) {
  int g = blockIdx.x;
  int k = threadIdx.x;
  int lo = 0, hi = N_NODES;
  while (lo < hi) { int m = (lo + hi) >> 1; if (ids[m] < g) lo = m + 1; else hi = m; }
  int s = lo;
  hi = N_NODES;
  while (lo < hi) { int m = (lo + hi) >> 1; if (ids[m] < g + 1) lo = m + 1; else hi = m; }
  int e = lo;
  float c = (float)(e - s);
  sigma[g * 256 + k] = __float2bfloat16(sums[g * 256 + k] / fmaxf(c, 1.f));
}

// R8 gemm (green): only for sh = sigma @ agWT + agb  [1024x256 x 256x512]
template<int ACT, int BF16OUT>
__global__ __launch_bounds__(256)
void gemm_mfma(const __hip_bfloat16* __restrict__ A,
               const __hip_bfloat16* __restrict__ BT,
               const float* __restrict__ bias,
               void* __restrict__ out, int K, int P) {
  __shared__ __attribute__((aligned(128))) char smem[81920];
  const int tid  = threadIdx.x;
  const int lane = tid & 63;
  const int wave = tid >> 6;
  const int bcol = blockIdx.x << 7;
  const int brow = blockIdx.y << 7;
  const int wm = (wave >> 1) << 6;
  const int wn = (wave & 1) << 6;
  const int lrow = lane >> 2;
  const int gc   = (lane & 3) ^ ((lane >> 3) & 3);
  f32x4 acc[4][4] = {};
  const int nt = K >> 5;
  auto STAGE = [&](int t) {
    char* sA = smem + (t % 5) * 16384;
    char* sB = sA + 8192;
    const int k0 = t << 5;
#pragma unroll
    for (int i = 0; i < 2; ++i) {
      int seg = (wave << 1) + i;
      int row = (seg << 4) + lrow;
      gll16(A + (size_t)(brow + row) * K + (k0 + (gc << 3)), sA + (seg << 10));
      gll16(BT + (size_t)(bcol + row) * K + (k0 + (gc << 3)), sB + (seg << 10));
    }
  };
  STAGE(0); STAGE(1); STAGE(2);
  const int r15 = lane & 15;
  const int c   = lane >> 4;
  for (int t = 0; t < nt; ++t) {
    if (t + 3 < nt) STAGE(t + 3);
    const int rem = nt - 1 - t;
    if (rem >= 3)      asm volatile("s_waitcnt vmcnt(12)" ::: "memory");
    else if (rem == 2) asm volatile("s_waitcnt vmcnt(8)"  ::: "memory");
    else if (rem == 1) asm volatile("s_waitcnt vmcnt(4)"  ::: "memory");
    else               asm volatile("s_waitcnt vmcnt(0)"  ::: "memory");
    __builtin_amdgcn_s_barrier();
    __builtin_amdgcn_sched_barrier(0);
    char* sA = smem + (t % 5) * 16384;
    char* sB = sA + 8192;
    bf16x8 af[4], bfv[4];
#pragma unroll
    for (int f = 0; f < 4; ++f) {
      int ar = wm + (f << 4) + r15;
      af[f]  = *reinterpret_cast<const bf16x8*>(sA + ar * 64 + ((c ^ ((ar >> 1) & 3)) << 4));
      int br = wn + (f << 4) + r15;
      bfv[f] = *reinterpret_cast<const bf16x8*>(sB + br * 64 + ((c ^ ((br >> 1) & 3)) << 4));
    }
#pragma unroll
    for (int fm = 0; fm < 4; ++fm)
#pragma unroll
      for (int fn = 0; fn < 4; ++fn)
        acc[fm][fn] = __builtin_amdgcn_mfma_f32_16x16x32_bf16(af[fm], bfv[fn], acc[fm][fn], 0, 0, 0);
  }
  const int hi4 = (lane >> 4) << 2;
#pragma unroll
  for (int fn = 0; fn < 4; ++fn) {
    int col = bcol + wn + (fn << 4) + r15;
    float bv = bias[col];
#pragma unroll
    for (int fm = 0; fm < 4; ++fm) {
      int row0 = brow + wm + (fm << 4) + hi4;
#pragma unroll
      for (int r = 0; r < 4; ++r) {
        float v = acc[fm][fn][r] + bv;
        if (ACT) v = lrelu_f(v);
        size_t oidx = (size_t)(row0 + r) * P + col;
        if (BF16OUT) reinterpret_cast<__hip_bfloat16*>(out)[oidx] = __float2bfloat16(v);
        else         reinterpret_cast<float*>(out)[oidx] = v;
      }
    }
  }
}

// ---------------- fused layer-chain v3 ----------------
// act LDS [128 nodes][512 k] bf16: addr(nd,kc) = nd*1024 + ((kc^(nd&7))<<4).
// wring: 3 slots x 8192B; slab s (k8 x P granules) -> slot s%3, addr p*16.
// MODE: 0 bias+lrelu->act; 1 +sh[bids] gather; 2 ge-final + fused seg-sum.
template<int K, int P, int MODE>
__device__ __forceinline__ void layer3(
    char* actmem, char* wring, const __hip_bfloat16* __restrict__ WTs,
    const float* __restrict__ bias, const float* __restrict__ sh,
    const int* __restrict__ ids, float* __restrict__ gout, int nbase, int tid) {
  const int w = tid >> 6, lane = tid & 63;
  const int l31 = lane & 31, hi = lane >> 5;
  constexpr int NS = K / 8, NU = K / 16;
  constexpr int MF = P / 256;            // 2 (P=512) or 1 (P=256)
  const int p0w = w * (P >> 3);

  f32x16 acc[MF][4];
#pragma unroll
  for (int a = 0; a < MF; ++a)
#pragma unroll
    for (int b = 0; b < 4; ++b)
#pragma unroll
      for (int e = 0; e < 16; ++e) acc[a][b][e] = 0.f;

  auto stage = [&](int s) {
    if (tid < P) gll16(WTs + (((size_t)s * P + tid) << 3), wring + (s % 3) * 8192 + (tid << 4));
  };

  stage(0); stage(1);

#pragma unroll
  for (int u = 0; u < NU; ++u) {
    if (2 * u + 2 < NS) { stage(2 * u + 2); asm volatile("s_waitcnt vmcnt(1)" ::: "memory"); }
    else                {                   asm volatile("s_waitcnt vmcnt(0)" ::: "memory"); }
    __builtin_amdgcn_s_barrier();           // all waves: slabs 2u,2u+1 landed
    __builtin_amdgcn_sched_barrier(0);
    const int slotA = (2 * u) % 3, slotB = (2 * u + 1) % 3;
    char* wslot = wring + (hi ? slotB : slotA) * 8192;
    bf16x8 wf[MF], af[4];
#pragma unroll
    for (int mi = 0; mi < MF; ++mi)
      wf[mi] = *reinterpret_cast<const bf16x8*>(wslot + ((p0w + mi * 32 + l31) << 4));
#pragma unroll
    for (int ni = 0; ni < 4; ++ni) {
      int nd = (ni << 5) + l31;
      int kc = 2 * u + hi;
      af[ni] = *reinterpret_cast<const bf16x8*>(actmem + (nd << 10) + ((kc ^ (nd & 7)) << 4));
    }
    asm volatile("s_waitcnt lgkmcnt(0)" ::: "memory");
    __builtin_amdgcn_sched_barrier(0);      // rule 18: no MFMA hoist above lgkm
    __builtin_amdgcn_s_barrier();           // all waves' reads done -> ring safe
    if (2 * u + 3 < NS) stage(2 * u + 3);   // overwrites slab 2u's slot
    __builtin_amdgcn_s_setprio(1);
#pragma unroll
    for (int mi = 0; mi < MF; ++mi)
#pragma unroll
      for (int ni = 0; ni < 4; ++ni)
        acc[mi][ni] = __builtin_amdgcn_mfma_f32_32x32x16_bf16(wf[mi], af[ni], acc[mi][ni], 0, 0, 0);
    __builtin_amdgcn_s_setprio(0);
  }

  // epilogue: D col=l&31 (node), row=(reg&3)+8*(reg>>2)+4*hi (neuron-local)
#pragma unroll
  for (int mi = 0; mi < MF; ++mi) {
    const int P0 = p0w + mi * 32;
#pragma unroll
    for (int ni = 0; ni < 4; ++ni) {
      const int n = (ni << 5) + l31;
      int gg = 0;
      if constexpr (MODE == 1) gg = ids[nbase + n];
#pragma unroll
      for (int q = 0; q < 4; ++q) {
        const int pb = P0 + (q << 3) + (hi << 2);
        f32x4 bv = *reinterpret_cast<const f32x4*>(bias + pb);
        f32x4 v;
        v[0] = acc[mi][ni][q * 4 + 0] + bv[0];
        v[1] = acc[mi][ni][q * 4 + 1] + bv[1];
        v[2] = acc[mi][ni][q * 4 + 2] + bv[2];
        v[3] = acc[mi][ni][q * 4 + 3] + bv[3];
        if constexpr (MODE == 1) {
          f32x4 s = *reinterpret_cast<const f32x4*>(sh + ((size_t)gg << 9) + pb);
          v = v + s;
        }
        short4 uq;
        uq.x = f2bs(lrelu_f(v[0])); uq.y = f2bs(lrelu_f(v[1]));
        uq.z = f2bs(lrelu_f(v[2])); uq.w = f2bs(lrelu_f(v[3]));
        const int kcp = (P0 >> 3) + q;
        *reinterpret_cast<short4*>(actmem + (n << 10) + ((kcp ^ (n & 7)) << 4) + (hi << 3)) = uq;
      }
    }
  }
  __syncthreads();   // act visible to next layer / seg-sum

  if constexpr (MODE == 2) {
    // fused segment-sum of ne (=act[128][256]) -> atomicAdd into gout=sums
    const int c = tid & 255, h = tid >> 8;   // h in {0,1}, 64 rows each
    float a = 0.f;
    int gp = ids[nbase + (h << 6)];
    for (int r = 0; r < 64; ++r) {
      int nd = (h << 6) + r;
      int ch = (c >> 3) ^ (nd & 7);
      unsigned short uv = *reinterpret_cast<const unsigned short*>(
          actmem + (nd << 10) + (ch << 4) + ((c & 7) << 1));
      float v = bs2f(uv);
      int g = ids[nbase + nd];
      if (g != gp) { atomicAdd(gout + ((size_t)gp << 8) + c, a); a = 0.f; gp = g; }
      a += v;
    }
    atomicAdd(gout + ((size_t)gp << 8) + c, a);
  }
}

// psi-final: K=512 -> P=128, f32 out via act-LDS transpose for coalesced d_out.
__device__ __forceinline__ void layer3_final(
    char* actmem, char* wring, const __hip_bfloat16* __restrict__ WTs,
    const float* __restrict__ bias, float* __restrict__ gout, int nbase, int tid) {
  const int w = tid >> 6, lane = tid & 63;
  const int l31 = lane & 31, hi = lane >> 5;
  constexpr int NS = 64, NU = 32, P = 128;
  const int mi = w & 3, ni0 = w >> 2;      // wave: m-frag mi, n-frags {ni0, ni0+2}
  const int P0 = mi << 5;

  f32x16 acc[2];
#pragma unroll
  for (int b = 0; b < 2; ++b)
#pragma unroll
    for (int e = 0; e < 16; ++e) acc[b][e] = 0.f;

  auto stage = [&](int s) {
    if (tid < P) gll16(WTs + (((size_t)s * P + tid) << 3), wring + (s % 3) * 8192 + (tid << 4));
  };
  stage(0); stage(1);

#pragma unroll
  for (int u = 0; u < NU; ++u) {
    if (2 * u + 2 < NS) { stage(2 * u + 2); asm volatile("s_waitcnt vmcnt(1)" ::: "memory"); }
    else                {                   asm volatile("s_waitcnt vmcnt(0)" ::: "memory"); }
    __builtin_amdgcn_s_barrier();
    __builtin_amdgcn_sched_barrier(0);
    const int slotA = (2 * u) % 3, slotB = (2 * u + 1) % 3;
    char* wslot = wring + (hi ? slotB : slotA) * 8192;
    bf16x8 wf = *reinterpret_cast<const bf16x8*>(wslot + ((P0 + l31) << 4));
    bf16x8 af[2];
#pragma unroll
    for (int j = 0; j < 2; ++j) {
      int nd = ((ni0 + (j << 1)) << 5) + l31;
      int kc = 2 * u + hi;
      af[j] = *reinterpret_cast<const bf16x8*>(actmem + (nd << 10) + ((kc ^ (nd & 7)) << 4));
    }
    asm volatile("s_waitcnt lgkmcnt(0)" ::: "memory");
    __builtin_amdgcn_sched_barrier(0);
    __builtin_amdgcn_s_barrier();
    if (2 * u + 3 < NS) stage(2 * u + 3);
    __builtin_amdgcn_s_setprio(1);
#pragma unroll
    for (int j = 0; j < 2; ++j)
      acc[j] = __builtin_amdgcn_mfma_f32_32x32x16_bf16(wf, af[j], acc[j], 0, 0, 0);
    __builtin_amdgcn_s_setprio(0);
  }

  // write f32 tile into act LDS (freed), swizzled: [128 n][32 pg of 16B]
#pragma unroll
  for (int j = 0; j < 2; ++j) {
    const int n = ((ni0 + (j << 1)) << 5) + l31;
#pragma unroll
    for (int q = 0; q < 4; ++q) {
      const int pb = P0 + (q << 3) + (hi << 2);
      f32x4 bv = *reinterpret_cast<const f32x4*>(bias + pb);
      f32x4 v;
      v[0] = acc[j][q * 4 + 0] + bv[0];
      v[1] = acc[j][q * 4 + 1] + bv[1];
      v[2] = acc[j][q * 4 + 2] + bv[2];
      v[3] = acc[j][q * 4 + 3] + bv[3];
      const int pg = (pb >> 2);            // 16B granule index, 0..31
      *reinterpret_cast<f32x4*>(actmem + (n << 9) + ((pg ^ ((n & 7) << 2)) << 4)) = v;
    }
  }
  __syncthreads();
  // coalesced copy-out: 4096 granules, 8/thread
#pragma unroll
  for (int i = 0; i < 8; ++i) {
    int fg = (i << 9) + tid;
    int n = fg >> 5, pg = fg & 31;
    f32x4 v = *reinterpret_cast<const f32x4*>(actmem + (n << 9) + ((pg ^ ((n & 7) << 2)) << 4));
    *reinterpret_cast<f32x4*>(gout + (((size_t)(nbase + n)) << 7) + (pg << 2)) = v;
  }
}

template<int PSI>
__global__ __launch_bounds__(512, 2)
void fused_chain3(const float* __restrict__ x, const int* __restrict__ bids,
                  const __hip_bfloat16* __restrict__ Wa, const float* __restrict__ ba,
                  const __hip_bfloat16* __restrict__ Wb, const float* __restrict__ bb,
                  const __hip_bfloat16* __restrict__ Wc, const float* __restrict__ bc,
                  const __hip_bfloat16* __restrict__ Wd, const float* __restrict__ bd,
                  const __hip_bfloat16* __restrict__ We, const float* __restrict__ be,
                  const float* __restrict__ sh, float* __restrict__ gout) {
  __shared__ __attribute__((aligned(128))) char actmem[131072];
  __shared__ __attribute__((aligned(128))) char wring[24576];
  const int tid = threadIdx.x;
  const int nbase = blockIdx.x << 7;

  // stage x[128][128] f32 -> act bf16 swizzled (2048 granules, 4/thread)
#pragma unroll
  for (int i = 0; i < 4; ++i) {
    int L = (i << 9) + tid;
    int n = L >> 4, c = L & 15;
    const float* xp = x + (((size_t)(nbase + n)) << 7) + (c << 3);
    float4 v0 = *reinterpret_cast<const float4*>(xp);
    float4 v1 = *reinterpret_cast<const float4*>(xp + 4);
    bf16x8 pk;
    pk[0] = f2bs(v0.x); pk[1] = f2bs(v0.y); pk[2] = f2bs(v0.z); pk[3] = f2bs(v0.w);
    pk[4] = f2bs(v1.x); pk[5] = f2bs(v1.y); pk[6] = f2bs(v1.z); pk[7] = f2bs(v1.w);
    *reinterpret_cast<bf16x8*>(actmem + (n << 10) + ((c ^ (n & 7)) << 4)) = pk;
  }
  __syncthreads();

  if constexpr (PSI == 0) {
    layer3<128, 512, 0>(actmem, wring, Wa, ba, nullptr, bids, nullptr, nbase, tid);
    layer3<512, 512, 0>(actmem, wring, Wb, bb, nullptr, bids, nullptr, nbase, tid);
    layer3<512, 512, 0>(actmem, wring, Wc, bc, nullptr, bids, nullptr, nbase, tid);
    layer3<512, 256, 2>(actmem, wring, Wd, bd, nullptr, bids, gout, nbase, tid);
  } else {
    layer3<128, 512, 1>(actmem, wring, Wa, ba, sh, bids, nullptr, nbase, tid);
    layer3<512, 512, 0>(actmem, wring, Wb, bb, nullptr, bids, nullptr, nbase, tid);
    layer3<512, 512, 0>(actmem, wring, Wc, bc, nullptr, bids, nullptr, nbase, tid);
    layer3<512, 512, 0>(actmem, wring, Wd, bd, nullptr, bids, nullptr, nbase, tid);
    layer3_final(actmem, wring, We, be, gout, nbase, tid);
  }
}

extern "C" void kernel_launch(void* const* d_in, const int* in_sizes, int n_in,
                              void* d_out, int out_size, void* d_ws, size_t ws_size,
                              hipStream_t stream) {
  const float* x      = (const float*)d_in[0];
  const int*   bids   = (const int*)  d_in[1];
  const float* ge_W0  = (const float*)d_in[2];
  const float* ge_b0  = (const float*)d_in[3];
  const float* ge_Wh  = (const float*)d_in[4];
  const float* ge_bh  = (const float*)d_in[5];
  const float* ge_Wo  = (const float*)d_in[6];
  const float* ge_bo  = (const float*)d_in[7];
  const float* in_W   = (const float*)d_in[8];
  const float* in_b   = (const float*)d_in[9];
  const float* ag_W   = (const float*)d_in[10];
  const float* ag_b   = (const float*)d_in[11];
  const float* psi_Wh = (const float*)d_in[12];
  const float* psi_bh = (const float*)d_in[13];
  const float* psi_Wo = (const float*)d_in[14];
  const float* psi_bo = (const float*)d_in[15];

  char* ws = (char*)d_ws;
  __hip_bfloat16* geW0C   = (__hip_bfloat16*)(ws + 0);        // slab [16][512]
  __hip_bfloat16* geWh0C  = (__hip_bfloat16*)(ws + 131072);   // [64][512]
  __hip_bfloat16* geWh1C  = (__hip_bfloat16*)(ws + 655360);
  __hip_bfloat16* geWoC   = (__hip_bfloat16*)(ws + 1179648);  // [64][256]
  __hip_bfloat16* inWC    = (__hip_bfloat16*)(ws + 1441792);  // [16][512]
  __hip_bfloat16* agWT    = (__hip_bfloat16*)(ws + 1572864);  // OLD layout [512][256]
  __hip_bfloat16* psiWh0C = (__hip_bfloat16*)(ws + 1835008);
  __hip_bfloat16* psiWh1C = (__hip_bfloat16*)(ws + 2359296);
  __hip_bfloat16* psiWh2C = (__hip_bfloat16*)(ws + 2883584);
  __hip_bfloat16* psiWoC  = (__hip_bfloat16*)(ws + 3407872);  // [64][128]
  __hip_bfloat16* sigma   = (__hip_bfloat16*)(ws + 3538944);  // [1024][256] bf16
  float*          sh      = (float*)         (ws + 4063232);  // [1024][512] f32
  float*          sums    = (float*)         (ws + 6160384);  // [1024][256] f32

  if (ws_size < 7340032) {
    sentinel<<<1, 64, 0, stream>>>((float*)d_out, 100000000.f + (float)(ws_size / 1024));
    return;
  }

  dim3 blk(256);
  hipMemsetAsync(sums, 0, NUM_G * 256 * sizeof(float), stream);

  // ---- weight conversions ----
  wt_convC<9><<<256,  blk, 0, stream>>>(ge_W0,           geW0C);
  wt_convC<9><<<1024, blk, 0, stream>>>(ge_Wh,           geWh0C);
  wt_convC<9><<<1024, blk, 0, stream>>>(ge_Wh + 262144,  geWh1C);
  wt_convC<8><<<512,  blk, 0, stream>>>(ge_Wo,           geWoC);
  wt_convC<9><<<256,  blk, 0, stream>>>(in_W,            inWC);
  wt_conv<<<dim3(16, 8), blk, 0, stream>>>(ag_W, agWT, 256, 512);   // old layout
  wt_convC<9><<<1024, blk, 0, stream>>>(psi_Wh,          psiWh0C);
  wt_convC<9><<<1024, blk, 0, stream>>>(psi_Wh + 262144, psiWh1C);
  wt_convC<9><<<1024, blk, 0, stream>>>(psi_Wh + 524288, psiWh2C);
  wt_convC<7><<<256,  blk, 0, stream>>>(psi_Wo,          psiWoC);

  // ---- ge chain fused (writes segment sums) ----
  fused_chain3<0><<<N_NODES / 128, 512, 0, stream>>>(
      x, bids, geW0C, ge_b0, geWh0C, ge_bh, geWh1C, ge_bh + 512, geWoC, ge_bo,
      nullptr, nullptr, nullptr, sums);

  // ---- sigma; sh = sigma @ agWT + agb ----
  sigma_fin<<<NUM_G, blk, 0, stream>>>(sums, bids, sigma);
  gemm_mfma<0, 0><<<dim3(4, 8), blk, 0, stream>>>(sigma, agWT, ag_b, sh, 256, 512);

  // ---- psi chain fused (writes d_out) ----
  fused_chain3<1><<<N_NODES / 128, 512, 0, stream>>>(
      x, bids, inWC, in_b, psiWh0C, psi_bh, psiWh1C, psi_bh + 512,
      psiWh2C, psi_bh + 1024, psiWoC, psi_bo, sh, (float*)d_out);
}

// Round 14
// 599.233 us; speedup vs baseline: 1.7785x; 1.7785x over previous
//
#include <hip/hip_runtime.h>
#include <hip/hip_bf16.h>

// Sumformer inner block -- R14: R13's wave-private weight staging + ONE raw
// s_barrier per K-tile. R13 (barrier-free) failed at 3.5e-3 (partial
// corruption, mechanism unidentified). The loop-top barrier restores the
// R8-proven ring-safety argument: reads(t-1) are consumed (lgkm-complete)
// before each wave's barrier(t); stage(t+1) -- which overwrites the t-1
// buffer -- is issued only after barrier(t). Counted per-wave vmcnt keeps
// loads in flight across the barrier (T4); setprio(1) wraps the MFMA
// cluster (T5). One barrier/tile vs R9's two.

typedef __attribute__((ext_vector_type(8))) short bf16x8;
typedef __attribute__((ext_vector_type(4))) float f32x4;

#define N_NODES 131072
#define NUM_G   1024

__device__ __forceinline__ float lrelu_f(float v) { return v >= 0.f ? v : 0.01f * v; }
__device__ __forceinline__ short f2bs(float f) {
  union { __hip_bfloat16 h; short s; } q; q.h = __float2bfloat16(f); return q.s;
}
__device__ __forceinline__ float bs2f(unsigned short u) {
  unsigned x = ((unsigned)u) << 16; return __uint_as_float(x);
}
__device__ __forceinline__ void gll16(const __hip_bfloat16* g, char* l) {
  __builtin_amdgcn_global_load_lds((const __attribute__((address_space(1))) void*)g,
                                   (__attribute__((address_space(3))) void*)l, 16, 0, 0);
}

__global__ void sentinel(float* out, float v) {
  if (blockIdx.x == 0 && threadIdx.x == 0) out[0] = v;
}

// Old layout (for gemm_mfma only): WT[p][k] = bf16(W[k][p])
__global__ void wt_conv(const float* __restrict__ W, __hip_bfloat16* __restrict__ WT, int K, int P) {
  __shared__ float tile[32][33];
  const int p0 = blockIdx.x << 5, k0 = blockIdx.y << 5;
  const int tx = threadIdx.x & 31, ty = threadIdx.x >> 5;
#pragma unroll
  for (int i = 0; i < 4; ++i) {
    int r = ty + (i << 3);
    tile[r][tx] = W[(size_t)(k0 + r) * P + p0 + tx];
  }
  __syncthreads();
#pragma unroll
  for (int i = 0; i < 4; ++i) {
    int r = ty + (i << 3);
    WT[(size_t)(p0 + r) * K + k0 + tx] = __float2bfloat16(tile[tx][r]);
  }
}

// Slab-granule layout: granule (k>>3)*P + p holds W[8*(k>>3)..+7][p] bf16x8.
template<int SHIFT>   // SHIFT = log2(P)
__global__ void wt_convC(const float* __restrict__ W, __hip_bfloat16* __restrict__ WTc) {
  int idx = blockIdx.x * 256 + threadIdx.x;
  int p = idx & ((1 << SHIFT) - 1);
  int k = idx >> SHIFT;
  WTc[((size_t)((k >> 3) << SHIFT) + p) * 8 + (k & 7)] = __float2bfloat16(W[idx]);
}

__global__ void sigma_fin(const float* __restrict__ sums,
                          const int* __restrict__ ids,
                          __hip_bfloat16* __restrict__ sigma) {
  int g = blockIdx.x;
  int k = threadIdx.x;
  int lo = 0, hi = N_NODES;
  while (lo < hi) { int m = (lo + hi) >> 1; if (ids[m] < g) lo = m + 1; else hi = m; }
  int s = lo;
  hi = N_NODES;
  while (lo < hi) { int m = (lo + hi) >> 1; if (ids[m] < g + 1) lo = m + 1; else hi = m; }
  int e = lo;
  float c = (float)(e - s);
  sigma[g * 256 + k] = __float2bfloat16(sums[g * 256 + k] / fmaxf(c, 1.f));
}

// R8 gemm (green): only for sh = sigma @ agWT + agb  [1024x256 x 256x512]
template<int ACT, int BF16OUT>
__global__ __launch_bounds__(256)
void gemm_mfma(const __hip_bfloat16* __restrict__ A,
               const __hip_bfloat16* __restrict__ BT,
               const float* __restrict__ bias,
               void* __restrict__ out, int K, int P) {
  __shared__ __attribute__((aligned(128))) char smem[81920];
  const int tid  = threadIdx.x;
  const int lane = tid & 63;
  const int wave = tid >> 6;
  const int bcol = blockIdx.x << 7;
  const int brow = blockIdx.y << 7;
  const int wm = (wave >> 1) << 6;
  const int wn = (wave & 1) << 6;
  const int lrow = lane >> 2;
  const int gc   = (lane & 3) ^ ((lane >> 3) & 3);
  f32x4 acc[4][4] = {};
  const int nt = K >> 5;
  auto STAGE = [&](int t) {
    char* sA = smem + (t % 5) * 16384;
    char* sB = sA + 8192;
    const int k0 = t << 5;
#pragma unroll
    for (int i = 0; i < 2; ++i) {
      int seg = (wave << 1) + i;
      int row = (seg << 4) + lrow;
      gll16(A + (size_t)(brow + row) * K + (k0 + (gc << 3)), sA + (seg << 10));
      gll16(BT + (size_t)(bcol + row) * K + (k0 + (gc << 3)), sB + (seg << 10));
    }
  };
  STAGE(0); STAGE(1); STAGE(2);
  const int r15 = lane & 15;
  const int c   = lane >> 4;
  for (int t = 0; t < nt; ++t) {
    if (t + 3 < nt) STAGE(t + 3);
    const int rem = nt - 1 - t;
    if (rem >= 3)      asm volatile("s_waitcnt vmcnt(12)" ::: "memory");
    else if (rem == 2) asm volatile("s_waitcnt vmcnt(8)"  ::: "memory");
    else if (rem == 1) asm volatile("s_waitcnt vmcnt(4)"  ::: "memory");
    else               asm volatile("s_waitcnt vmcnt(0)"  ::: "memory");
    __builtin_amdgcn_s_barrier();
    __builtin_amdgcn_sched_barrier(0);
    char* sA = smem + (t % 5) * 16384;
    char* sB = sA + 8192;
    bf16x8 af[4], bfv[4];
#pragma unroll
    for (int f = 0; f < 4; ++f) {
      int ar = wm + (f << 4) + r15;
      af[f]  = *reinterpret_cast<const bf16x8*>(sA + ar * 64 + ((c ^ ((ar >> 1) & 3)) << 4));
      int br = wn + (f << 4) + r15;
      bfv[f] = *reinterpret_cast<const bf16x8*>(sB + br * 64 + ((c ^ ((br >> 1) & 3)) << 4));
    }
#pragma unroll
    for (int fm = 0; fm < 4; ++fm)
#pragma unroll
      for (int fn = 0; fn < 4; ++fn)
        acc[fm][fn] = __builtin_amdgcn_mfma_f32_16x16x32_bf16(af[fm], bfv[fn], acc[fm][fn], 0, 0, 0);
  }
  const int hi4 = (lane >> 4) << 2;
#pragma unroll
  for (int fn = 0; fn < 4; ++fn) {
    int col = bcol + wn + (fn << 4) + r15;
    float bv = bias[col];
#pragma unroll
    for (int fm = 0; fm < 4; ++fm) {
      int row0 = brow + wm + (fm << 4) + hi4;
#pragma unroll
      for (int r = 0; r < 4; ++r) {
        float v = acc[fm][fn][r] + bv;
        if (ACT) v = lrelu_f(v);
        size_t oidx = (size_t)(row0 + r) * P + col;
        if (BF16OUT) reinterpret_cast<__hip_bfloat16*>(out)[oidx] = __float2bfloat16(v);
        else         reinterpret_cast<float*>(out)[oidx] = v;
      }
    }
  }
}

// ---------------- fused layer-chain v5: 1 barrier/tile, wave-private ring ----
// act LDS [64 nodes][512 k] bf16: addr(nd,kc) = nd*1024 + ((kc^(nd&7))<<4).
// Per-wave weight dbuf: wring + w*8192 + (t&1)*4096; slab = [4 khi][PW p]
// granules of 16B. MODE: 0 bias+lrelu->act; 1 +sh gather; 2 ge-final+seg-sum;
// 3 psi-final -> d_out f32.
template<int K, int P, int MODE>
__device__ __forceinline__ void layer5(
    char* actmem, char* wring, const __hip_bfloat16* __restrict__ WTs,
    const float* __restrict__ bias, const float* __restrict__ sh,
    const int* bids_lds, float* __restrict__ gout, int nbase, int tid) {
  const int w = tid >> 6, lane = tid & 63;
  const int r15 = lane & 15, khi = lane >> 4;
  constexpr int PW  = P >> 3;          // neurons per wave
  constexpr int MF  = PW >> 4;         // m-frags per wave (4/2/1)
  constexpr int LPL = PW >> 4;         // gload_lds per lane per tile
  constexpr int LPW = (PW == 64) ? 6 : (PW == 32) ? 5 : 4;  // log2(PW)
  constexpr int NT  = K >> 5;
  const int p0w = w * PW;
  char* const wbase = wring + (w << 13);

  f32x4 acc[MF][4];
#pragma unroll
  for (int a = 0; a < MF; ++a)
#pragma unroll
    for (int b = 0; b < 4; ++b) acc[a][b] = f32x4{0.f, 0.f, 0.f, 0.f};

  auto stage = [&](int t) {
    char* wb = wbase + ((t & 1) << 12);
    const int sb = t << 2;             // slab base (k8 slabs)
#pragma unroll
    for (int i = 0; i < LPL; ++i) {
      int g = (i << 6) + lane;
      int kg = g >> LPW, pl = g & (PW - 1);
      gll16(WTs + (((size_t)(sb + kg) * P) + p0w + pl) * 8, wb + (i << 10));
    }
  };

  stage(0);
#pragma unroll
  for (int t = 0; t < NT; ++t) {
    // One barrier per tile: all waves' reads(t-1) are lgkm-complete before
    // any wave issues stage(t+1) (which overwrites the t-1 buffer).
    __builtin_amdgcn_s_barrier();
    if (t + 1 < NT) {
      stage(t + 1);
      if constexpr (LPL == 4)      asm volatile("s_waitcnt vmcnt(4)" ::: "memory");
      else if constexpr (LPL == 2) asm volatile("s_waitcnt vmcnt(2)" ::: "memory");
      else                         asm volatile("s_waitcnt vmcnt(1)" ::: "memory");
    } else {
      asm volatile("s_waitcnt vmcnt(0)" ::: "memory");
    }
    __builtin_amdgcn_sched_barrier(0);   // no ds_read hoist above the wait

    char* wb = wbase + ((t & 1) << 12);
    bf16x8 af[MF], bf[4];
#pragma unroll
    for (int mi = 0; mi < MF; ++mi)
      af[mi] = *reinterpret_cast<const bf16x8*>(wb + (((khi << LPW) + (mi << 4) + r15) << 4));
#pragma unroll
    for (int ni = 0; ni < 4; ++ni) {
      int nd = (ni << 4) + r15;
      int ch = ((t << 2) + khi) ^ (nd & 7);
      bf[ni] = *reinterpret_cast<const bf16x8*>(actmem + (nd << 10) + (ch << 4));
    }
    __builtin_amdgcn_s_setprio(1);
#pragma unroll
    for (int mi = 0; mi < MF; ++mi)
#pragma unroll
      for (int ni = 0; ni < 4; ++ni)
        acc[mi][ni] = __builtin_amdgcn_mfma_f32_16x16x32_bf16(af[mi], bf[ni], acc[mi][ni], 0, 0, 0);
    __builtin_amdgcn_s_setprio(0);
  }

  // ---- epilogue: C/D col=node(lane&15), row=neuron((lane>>4)*4+reg) ----
  if constexpr (MODE == 3) {
    const int pb = p0w + (khi << 2);   // P=128, MF=1
    f32x4 bv = *reinterpret_cast<const f32x4*>(bias + pb);
#pragma unroll
    for (int ni = 0; ni < 4; ++ni) {
      int nd = (ni << 4) + r15;
      f32x4 v = acc[0][ni] + bv;
      *reinterpret_cast<f32x4*>(gout + ((size_t)(nbase + nd) << 7) + pb) = v;
    }
  } else {
    __syncthreads();   // all waves done reading act
#pragma unroll
    for (int mi = 0; mi < MF; ++mi) {
      const int pb = p0w + (mi << 4) + (khi << 2);
      f32x4 bv = *reinterpret_cast<const f32x4*>(bias + pb);
#pragma unroll
      for (int ni = 0; ni < 4; ++ni) {
        int nd = (ni << 4) + r15;
        f32x4 v = acc[mi][ni] + bv;
        if constexpr (MODE == 1) {
          int g = bids_lds[nd];
          f32x4 s = *reinterpret_cast<const f32x4*>(sh + ((size_t)g << 9) + pb);
          v = v + s;
        }
        short4 u;
        u.x = f2bs(lrelu_f(v[0])); u.y = f2bs(lrelu_f(v[1]));
        u.z = f2bs(lrelu_f(v[2])); u.w = f2bs(lrelu_f(v[3]));
        int ch = (pb >> 3) ^ (nd & 7);
        *reinterpret_cast<short4*>(actmem + (nd << 10) + (ch << 4) + ((pb & 4) << 1)) = u;
      }
    }
    __syncthreads();   // act visible to next layer / seg-sum

    if constexpr (MODE == 2) {
      // fused segment-sum of ne (=act[64][256]) -> atomicAdd into gout=sums
      const int c = tid & 255, h = tid >> 8;
      float a = 0.f;
      int gp = bids_lds[h << 5];
      for (int r = 0; r < 32; ++r) {
        int nd = (h << 5) + r;
        int ch = (c >> 3) ^ (nd & 7);
        unsigned short uv = *reinterpret_cast<const unsigned short*>(
            actmem + (nd << 10) + (ch << 4) + ((c & 7) << 1));
        float v = bs2f(uv);
        int g = bids_lds[nd];
        if (g != gp) { atomicAdd(gout + ((size_t)gp << 8) + c, a); a = 0.f; gp = g; }
        a += v;
      }
      atomicAdd(gout + ((size_t)gp << 8) + c, a);
    }
  }
}

template<int PSI>
__global__ __launch_bounds__(512, 1)
void fused_chain5(const float* __restrict__ x, const int* __restrict__ bids,
                  const __hip_bfloat16* __restrict__ Wa, const float* __restrict__ ba,
                  const __hip_bfloat16* __restrict__ Wb, const float* __restrict__ bb,
                  const __hip_bfloat16* __restrict__ Wc, const float* __restrict__ bc,
                  const __hip_bfloat16* __restrict__ Wd, const float* __restrict__ bd,
                  const __hip_bfloat16* __restrict__ We, const float* __restrict__ be,
                  const float* __restrict__ sh, float* __restrict__ gout) {
  __shared__ __attribute__((aligned(128))) char actmem[65536];
  __shared__ __attribute__((aligned(128))) char wring[65536];   // 8 waves x 8KB
  __shared__ int bids_lds[64];
  const int tid = threadIdx.x;
  const int nbase = blockIdx.x << 6;
  if (tid < 64) bids_lds[tid] = bids[nbase + tid];

  // stage x[64][128] f32 -> act bf16 swizzled
#pragma unroll
  for (int i = 0; i < 2; ++i) {
    int L = (i << 9) + tid;
    int n = L >> 4, c = L & 15;
    const float* xp = x + (((size_t)(nbase + n)) << 7) + (c << 3);
    float4 v0 = *reinterpret_cast<const float4*>(xp);
    float4 v1 = *reinterpret_cast<const float4*>(xp + 4);
    bf16x8 pk;
    pk[0] = f2bs(v0.x); pk[1] = f2bs(v0.y); pk[2] = f2bs(v0.z); pk[3] = f2bs(v0.w);
    pk[4] = f2bs(v1.x); pk[5] = f2bs(v1.y); pk[6] = f2bs(v1.z); pk[7] = f2bs(v1.w);
    *reinterpret_cast<bf16x8*>(actmem + (n << 10) + ((c ^ (n & 7)) << 4)) = pk;
  }
  __syncthreads();

  if constexpr (PSI == 0) {
    layer5<128, 512, 0>(actmem, wring, Wa, ba, nullptr, bids_lds, nullptr, nbase, tid);
    layer5<512, 512, 0>(actmem, wring, Wb, bb, nullptr, bids_lds, nullptr, nbase, tid);
    layer5<512, 512, 0>(actmem, wring, Wc, bc, nullptr, bids_lds, nullptr, nbase, tid);
    layer5<512, 256, 2>(actmem, wring, Wd, bd, nullptr, bids_lds, gout, nbase, tid);
  } else {
    layer5<128, 512, 1>(actmem, wring, Wa, ba, sh, bids_lds, nullptr, nbase, tid);
    layer5<512, 512, 0>(actmem, wring, Wb, bb, nullptr, bids_lds, nullptr, nbase, tid);
    layer5<512, 512, 0>(actmem, wring, Wc, bc, nullptr, bids_lds, nullptr, nbase, tid);
    layer5<512, 512, 0>(actmem, wring, Wd, bd, nullptr, bids_lds, nullptr, nbase, tid);
    layer5<512, 128, 3>(actmem, wring, We, be, nullptr, bids_lds, gout, nbase, tid);
  }
}

extern "C" void kernel_launch(void* const* d_in, const int* in_sizes, int n_in,
                              void* d_out, int out_size, void* d_ws, size_t ws_size,
                              hipStream_t stream) {
  const float* x      = (const float*)d_in[0];
  const int*   bids   = (const int*)  d_in[1];
  const float* ge_W0  = (const float*)d_in[2];
  const float* ge_b0  = (const float*)d_in[3];
  const float* ge_Wh  = (const float*)d_in[4];
  const float* ge_bh  = (const float*)d_in[5];
  const float* ge_Wo  = (const float*)d_in[6];
  const float* ge_bo  = (const float*)d_in[7];
  const float* in_W   = (const float*)d_in[8];
  const float* in_b   = (const float*)d_in[9];
  const float* ag_W   = (const float*)d_in[10];
  const float* ag_b   = (const float*)d_in[11];
  const float* psi_Wh = (const float*)d_in[12];
  const float* psi_bh = (const float*)d_in[13];
  const float* psi_Wo = (const float*)d_in[14];
  const float* psi_bo = (const float*)d_in[15];

  char* ws = (char*)d_ws;
  __hip_bfloat16* geW0C   = (__hip_bfloat16*)(ws + 0);        // slab [16][512]
  __hip_bfloat16* geWh0C  = (__hip_bfloat16*)(ws + 131072);   // [64][512]
  __hip_bfloat16* geWh1C  = (__hip_bfloat16*)(ws + 655360);
  __hip_bfloat16* geWoC   = (__hip_bfloat16*)(ws + 1179648);  // [64][256]
  __hip_bfloat16* inWC    = (__hip_bfloat16*)(ws + 1441792);  // [16][512]
  __hip_bfloat16* agWT    = (__hip_bfloat16*)(ws + 1572864);  // OLD layout [512][256]
  __hip_bfloat16* psiWh0C = (__hip_bfloat16*)(ws + 1835008);
  __hip_bfloat16* psiWh1C = (__hip_bfloat16*)(ws + 2359296);
  __hip_bfloat16* psiWh2C = (__hip_bfloat16*)(ws + 2883584);
  __hip_bfloat16* psiWoC  = (__hip_bfloat16*)(ws + 3407872);  // [64][128]
  __hip_bfloat16* sigma   = (__hip_bfloat16*)(ws + 3538944);  // [1024][256] bf16
  float*          sh      = (float*)         (ws + 4063232);  // [1024][512] f32
  float*          sums    = (float*)         (ws + 6160384);  // [1024][256] f32

  if (ws_size < 7340032) {
    sentinel<<<1, 64, 0, stream>>>((float*)d_out, 100000000.f + (float)(ws_size / 1024));
    return;
  }

  dim3 blk(256);
  hipMemsetAsync(sums, 0, NUM_G * 256 * sizeof(float), stream);

  // ---- weight conversions ----
  wt_convC<9><<<256,  blk, 0, stream>>>(ge_W0,           geW0C);
  wt_convC<9><<<1024, blk, 0, stream>>>(ge_Wh,           geWh0C);
  wt_convC<9><<<1024, blk, 0, stream>>>(ge_Wh + 262144,  geWh1C);
  wt_convC<8><<<512,  blk, 0, stream>>>(ge_Wo,           geWoC);
  wt_convC<9><<<256,  blk, 0, stream>>>(in_W,            inWC);
  wt_conv<<<dim3(16, 8), blk, 0, stream>>>(ag_W, agWT, 256, 512);   // old layout
  wt_convC<9><<<1024, blk, 0, stream>>>(psi_Wh,          psiWh0C);
  wt_convC<9><<<1024, blk, 0, stream>>>(psi_Wh + 262144, psiWh1C);
  wt_convC<9><<<1024, blk, 0, stream>>>(psi_Wh + 524288, psiWh2C);
  wt_convC<7><<<256,  blk, 0, stream>>>(psi_Wo,          psiWoC);

  // ---- ge chain fused (writes segment sums) ----
  fused_chain5<0><<<N_NODES / 64, 512, 0, stream>>>(
      x, bids, geW0C, ge_b0, geWh0C, ge_bh, geWh1C, ge_bh + 512, geWoC, ge_bo,
      nullptr, nullptr, nullptr, sums);

  // ---- sigma; sh = sigma @ agWT + agb ----
  sigma_fin<<<NUM_G, blk, 0, stream>>>(sums, bids, sigma);
  gemm_mfma<0, 0><<<dim3(4, 8), blk, 0, stream>>>(sigma, agWT, ag_b, sh, 256, 512);

  // ---- psi chain fused (writes d_out) ----
  fused_chain5<1><<<N_NODES / 64, 512, 0, stream>>>(
      x, bids, inWC, in_b, psiWh0C, psi_bh, psiWh1C, psi_bh + 512,
      psiWh2C, psi_bh + 1024, psiWoC, psi_bo, sh, (float*)d_out);
}

// Round 15
// 598.475 us; speedup vs baseline: 1.7808x; 1.0013x over previous
//
#include <hip/hip_runtime.h>
#include <hip/hip_bf16.h>

// Sumformer inner block -- R15: 128 nodes/block on the R14-proven pipeline.
// R14 post-mortem: LDS-volume-bound; intensity fixed by 64x64 wave tile.
// R15: wave tile 64 neurons x 128 nodes (acc[4][8]=128 VGPR; R12's spill was
// my __launch_bounds__(512,2) forcing VGPR<=128 -- here (512,1)).
// Weight ring = single 4KB buffer/wave: barrier -> vmcnt(0) [stage(t) was
// issued one MFMA-cluster ago] -> ds_read frags -> lgkm0 -> stage(t+1) into
// the same buffer (slab already in regs) -> setprio MFMAs. LDS = 128KB act +
// 32KB rings = exactly 160KB; bids read from global (L1-cached).

typedef __attribute__((ext_vector_type(8))) short bf16x8;
typedef __attribute__((ext_vector_type(4))) float f32x4;

#define N_NODES 131072
#define NUM_G   1024

__device__ __forceinline__ float lrelu_f(float v) { return v >= 0.f ? v : 0.01f * v; }
__device__ __forceinline__ short f2bs(float f) {
  union { __hip_bfloat16 h; short s; } q; q.h = __float2bfloat16(f); return q.s;
}
__device__ __forceinline__ float bs2f(unsigned short u) {
  unsigned x = ((unsigned)u) << 16; return __uint_as_float(x);
}
__device__ __forceinline__ void gll16(const __hip_bfloat16* g, char* l) {
  __builtin_amdgcn_global_load_lds((const __attribute__((address_space(1))) void*)g,
                                   (__attribute__((address_space(3))) void*)l, 16, 0, 0);
}

__global__ void sentinel(float* out, float v) {
  if (blockIdx.x == 0 && threadIdx.x == 0) out[0] = v;
}

// Old layout (for gemm_mfma only): WT[p][k] = bf16(W[k][p])
__global__ void wt_conv(const float* __restrict__ W, __hip_bfloat16* __restrict__ WT, int K, int P) {
  __shared__ float tile[32][33];
  const int p0 = blockIdx.x << 5, k0 = blockIdx.y << 5;
  const int tx = threadIdx.x & 31, ty = threadIdx.x >> 5;
#pragma unroll
  for (int i = 0; i < 4; ++i) {
    int r = ty + (i << 3);
    tile[r][tx] = W[(size_t)(k0 + r) * P + p0 + tx];
  }
  __syncthreads();
#pragma unroll
  for (int i = 0; i < 4; ++i) {
    int r = ty + (i << 3);
    WT[(size_t)(p0 + r) * K + k0 + tx] = __float2bfloat16(tile[tx][r]);
  }
}

// Slab-granule layout: granule (k>>3)*P + p holds W[8*(k>>3)..+7][p] bf16x8.
template<int SHIFT>   // SHIFT = log2(P)
__global__ void wt_convC(const float* __restrict__ W, __hip_bfloat16* __restrict__ WTc) {
  int idx = blockIdx.x * 256 + threadIdx.x;
  int p = idx & ((1 << SHIFT) - 1);
  int k = idx >> SHIFT;
  WTc[((size_t)((k >> 3) << SHIFT) + p) * 8 + (k & 7)] = __float2bfloat16(W[idx]);
}

__global__ void sigma_fin(const float* __restrict__ sums,
                          const int* __restrict__ ids,
                          __hip_bfloat16* __restrict__ sigma) {
  int g = blockIdx.x;
  int k = threadIdx.x;
  int lo = 0, hi = N_NODES;
  while (lo < hi) { int m = (lo + hi) >> 1; if (ids[m] < g) lo = m + 1; else hi = m; }
  int s = lo;
  hi = N_NODES;
  while (lo < hi) { int m = (lo + hi) >> 1; if (ids[m] < g + 1) lo = m + 1; else hi = m; }
  int e = lo;
  float c = (float)(e - s);
  sigma[g * 256 + k] = __float2bfloat16(sums[g * 256 + k] / fmaxf(c, 1.f));
}

// R8 gemm (green): only for sh = sigma @ agWT + agb  [1024x256 x 256x512]
template<int ACT, int BF16OUT>
__global__ __launch_bounds__(256)
void gemm_mfma(const __hip_bfloat16* __restrict__ A,
               const __hip_bfloat16* __restrict__ BT,
               const float* __restrict__ bias,
               void* __restrict__ out, int K, int P) {
  __shared__ __attribute__((aligned(128))) char smem[81920];
  const int tid  = threadIdx.x;
  const int lane = tid & 63;
  const int wave = tid >> 6;
  const int bcol = blockIdx.x << 7;
  const int brow = blockIdx.y << 7;
  const int wm = (wave >> 1) << 6;
  const int wn = (wave & 1) << 6;
  const int lrow = lane >> 2;
  const int gc   = (lane & 3) ^ ((lane >> 3) & 3);
  f32x4 acc[4][4] = {};
  const int nt = K >> 5;
  auto STAGE = [&](int t) {
    char* sA = smem + (t % 5) * 16384;
    char* sB = sA + 8192;
    const int k0 = t << 5;
#pragma unroll
    for (int i = 0; i < 2; ++i) {
      int seg = (wave << 1) + i;
      int row = (seg << 4) + lrow;
      gll16(A + (size_t)(brow + row) * K + (k0 + (gc << 3)), sA + (seg << 10));
      gll16(BT + (size_t)(bcol + row) * K + (k0 + (gc << 3)), sB + (seg << 10));
    }
  };
  STAGE(0); STAGE(1); STAGE(2);
  const int r15 = lane & 15;
  const int c   = lane >> 4;
  for (int t = 0; t < nt; ++t) {
    if (t + 3 < nt) STAGE(t + 3);
    const int rem = nt - 1 - t;
    if (rem >= 3)      asm volatile("s_waitcnt vmcnt(12)" ::: "memory");
    else if (rem == 2) asm volatile("s_waitcnt vmcnt(8)"  ::: "memory");
    else if (rem == 1) asm volatile("s_waitcnt vmcnt(4)"  ::: "memory");
    else               asm volatile("s_waitcnt vmcnt(0)"  ::: "memory");
    __builtin_amdgcn_s_barrier();
    __builtin_amdgcn_sched_barrier(0);
    char* sA = smem + (t % 5) * 16384;
    char* sB = sA + 8192;
    bf16x8 af[4], bfv[4];
#pragma unroll
    for (int f = 0; f < 4; ++f) {
      int ar = wm + (f << 4) + r15;
      af[f]  = *reinterpret_cast<const bf16x8*>(sA + ar * 64 + ((c ^ ((ar >> 1) & 3)) << 4));
      int br = wn + (f << 4) + r15;
      bfv[f] = *reinterpret_cast<const bf16x8*>(sB + br * 64 + ((c ^ ((br >> 1) & 3)) << 4));
    }
#pragma unroll
    for (int fm = 0; fm < 4; ++fm)
#pragma unroll
      for (int fn = 0; fn < 4; ++fn)
        acc[fm][fn] = __builtin_amdgcn_mfma_f32_16x16x32_bf16(af[fm], bfv[fn], acc[fm][fn], 0, 0, 0);
  }
  const int hi4 = (lane >> 4) << 2;
#pragma unroll
  for (int fn = 0; fn < 4; ++fn) {
    int col = bcol + wn + (fn << 4) + r15;
    float bv = bias[col];
#pragma unroll
    for (int fm = 0; fm < 4; ++fm) {
      int row0 = brow + wm + (fm << 4) + hi4;
#pragma unroll
      for (int r = 0; r < 4; ++r) {
        float v = acc[fm][fn][r] + bv;
        if (ACT) v = lrelu_f(v);
        size_t oidx = (size_t)(row0 + r) * P + col;
        if (BF16OUT) reinterpret_cast<__hip_bfloat16*>(out)[oidx] = __float2bfloat16(v);
        else         reinterpret_cast<float*>(out)[oidx] = v;
      }
    }
  }
}

// ---------------- fused layer-chain v6: 128 nodes, single-buffer ring ----
// act LDS [128 nodes][512 k] bf16: addr(nd,kc) = nd*1024 + ((kc^(nd&7))<<4).
// Per-wave weight buffer: wring + w*4096 (4KB, single); slab for tile t =
// granules (4t+kg)*P + p0w+pl, kg=0..3, pl=0..PW-1, at byte kg*1024+pl*16
// (PW=64) or packed by LPW. MODE: 0 bias+lrelu->act; 1 +sh gather;
// 2 ge-final+seg-sum; 3 psi-final -> d_out f32.
template<int K, int P, int MODE>
__device__ __forceinline__ void layer6(
    char* actmem, char* wring, const __hip_bfloat16* __restrict__ WTs,
    const float* __restrict__ bias, const float* __restrict__ sh,
    const int* __restrict__ ids, float* __restrict__ gout, int nbase, int tid) {
  const int w = tid >> 6, lane = tid & 63;
  const int r15 = lane & 15, khi = lane >> 4;
  constexpr int PW  = P >> 3;          // neurons per wave
  constexpr int MF  = PW >> 4;         // m-frags per wave (4/2/1)
  constexpr int LPL = PW >> 4;         // gload_lds per lane per tile
  constexpr int LPW = (PW == 64) ? 6 : (PW == 32) ? 5 : 4;  // log2(PW)
  constexpr int NT  = K >> 5;
  const int p0w = w * PW;
  char* const wb = wring + (w << 12);  // single 4KB (PW=64) buffer per wave

  f32x4 acc[MF][8];
#pragma unroll
  for (int a = 0; a < MF; ++a)
#pragma unroll
    for (int b = 0; b < 8; ++b) acc[a][b] = f32x4{0.f, 0.f, 0.f, 0.f};

  auto stage = [&](int t) {
    const int sb = t << 2;             // slab base (k8 slabs)
#pragma unroll
    for (int i = 0; i < LPL; ++i) {
      int g = (i << 6) + lane;
      int kg = g >> LPW, pl = g & (PW - 1);
      gll16(WTs + (((size_t)(sb + kg) * P) + p0w + pl) * 8, wb + (i << 10));
    }
  };

  stage(0);
#pragma unroll
  for (int t = 0; t < NT; ++t) {
    __builtin_amdgcn_s_barrier();                         // R14-proven lockstep
    asm volatile("s_waitcnt vmcnt(0)" ::: "memory");      // stage(t) landed
    __builtin_amdgcn_sched_barrier(0);

    bf16x8 af[MF], bf[8];
#pragma unroll
    for (int mi = 0; mi < MF; ++mi)
      af[mi] = *reinterpret_cast<const bf16x8*>(wb + (((khi << LPW) + (mi << 4) + r15) << 4));
#pragma unroll
    for (int ni = 0; ni < 8; ++ni) {
      int nd = (ni << 4) + r15;
      int ch = ((t << 2) + khi) ^ (nd & 7);
      bf[ni] = *reinterpret_cast<const bf16x8*>(actmem + (nd << 10) + (ch << 4));
    }
    asm volatile("s_waitcnt lgkmcnt(0)" ::: "memory");    // frags in regs
    __builtin_amdgcn_sched_barrier(0);                    // rule 18
    if (t + 1 < NT) stage(t + 1);                         // overwrite OK now

    __builtin_amdgcn_s_setprio(1);
#pragma unroll
    for (int mi = 0; mi < MF; ++mi)
#pragma unroll
      for (int ni = 0; ni < 8; ++ni)
        acc[mi][ni] = __builtin_amdgcn_mfma_f32_16x16x32_bf16(af[mi], bf[ni], acc[mi][ni], 0, 0, 0);
    __builtin_amdgcn_s_setprio(0);
  }

  // ---- epilogue: C/D col=node(lane&15), row=neuron((lane>>4)*4+reg) ----
  if constexpr (MODE == 3) {
    const int pb = p0w + (khi << 2);   // P=128, MF=1
    f32x4 bv = *reinterpret_cast<const f32x4*>(bias + pb);
#pragma unroll
    for (int ni = 0; ni < 8; ++ni) {
      int nd = (ni << 4) + r15;
      f32x4 v = acc[0][ni] + bv;
      *reinterpret_cast<f32x4*>(gout + ((size_t)(nbase + nd) << 7) + pb) = v;
    }
  } else {
    __syncthreads();   // all waves done reading act
#pragma unroll
    for (int mi = 0; mi < MF; ++mi) {
      const int pb = p0w + (mi << 4) + (khi << 2);
      f32x4 bv = *reinterpret_cast<const f32x4*>(bias + pb);
#pragma unroll
      for (int ni = 0; ni < 8; ++ni) {
        int nd = (ni << 4) + r15;
        f32x4 v = acc[mi][ni] + bv;
        if constexpr (MODE == 1) {
          int g = ids[nbase + nd];
          f32x4 s = *reinterpret_cast<const f32x4*>(sh + ((size_t)g << 9) + pb);
          v = v + s;
        }
        short4 u;
        u.x = f2bs(lrelu_f(v[0])); u.y = f2bs(lrelu_f(v[1]));
        u.z = f2bs(lrelu_f(v[2])); u.w = f2bs(lrelu_f(v[3]));
        int ch = (pb >> 3) ^ (nd & 7);
        *reinterpret_cast<short4*>(actmem + (nd << 10) + (ch << 4) + ((pb & 4) << 1)) = u;
      }
    }
    __syncthreads();   // act visible to next layer / seg-sum

    if constexpr (MODE == 2) {
      // fused segment-sum of ne (=act[128][256]) -> atomicAdd into gout=sums
      const int c = tid & 255, h = tid >> 8;   // h in {0,1}, 64 rows each
      float a = 0.f;
      int gp = ids[nbase + (h << 6)];
      for (int r = 0; r < 64; ++r) {
        int nd = (h << 6) + r;
        int ch = (c >> 3) ^ (nd & 7);
        unsigned short uv = *reinterpret_cast<const unsigned short*>(
            actmem + (nd << 10) + (ch << 4) + ((c & 7) << 1));
        float v = bs2f(uv);
        int g = ids[nbase + nd];
        if (g != gp) { atomicAdd(gout + ((size_t)gp << 8) + c, a); a = 0.f; gp = g; }
        a += v;
      }
      atomicAdd(gout + ((size_t)gp << 8) + c, a);
    }
  }
}

template<int PSI>
__global__ __launch_bounds__(512, 1)
void fused_chain6(const float* __restrict__ x, const int* __restrict__ bids,
                  const __hip_bfloat16* __restrict__ Wa, const float* __restrict__ ba,
                  const __hip_bfloat16* __restrict__ Wb, const float* __restrict__ bb,
                  const __hip_bfloat16* __restrict__ Wc, const float* __restrict__ bc,
                  const __hip_bfloat16* __restrict__ Wd, const float* __restrict__ bd,
                  const __hip_bfloat16* __restrict__ We, const float* __restrict__ be,
                  const float* __restrict__ sh, float* __restrict__ gout) {
  __shared__ __attribute__((aligned(128))) char actmem[131072];
  __shared__ __attribute__((aligned(128))) char wring[32768];   // 8 waves x 4KB
  const int tid = threadIdx.x;
  const int nbase = blockIdx.x << 7;

  // stage x[128][128] f32 -> act bf16 swizzled (2048 granules, 4/thread)
#pragma unroll
  for (int i = 0; i < 4; ++i) {
    int L = (i << 9) + tid;
    int n = L >> 4, c = L & 15;
    const float* xp = x + (((size_t)(nbase + n)) << 7) + (c << 3);
    float4 v0 = *reinterpret_cast<const float4*>(xp);
    float4 v1 = *reinterpret_cast<const float4*>(xp + 4);
    bf16x8 pk;
    pk[0] = f2bs(v0.x); pk[1] = f2bs(v0.y); pk[2] = f2bs(v0.z); pk[3] = f2bs(v0.w);
    pk[4] = f2bs(v1.x); pk[5] = f2bs(v1.y); pk[6] = f2bs(v1.z); pk[7] = f2bs(v1.w);
    *reinterpret_cast<bf16x8*>(actmem + (n << 10) + ((c ^ (n & 7)) << 4)) = pk;
  }
  __syncthreads();

  if constexpr (PSI == 0) {
    layer6<128, 512, 0>(actmem, wring, Wa, ba, nullptr, bids, nullptr, nbase, tid);
    layer6<512, 512, 0>(actmem, wring, Wb, bb, nullptr, bids, nullptr, nbase, tid);
    layer6<512, 512, 0>(actmem, wring, Wc, bc, nullptr, bids, nullptr, nbase, tid);
    layer6<512, 256, 2>(actmem, wring, Wd, bd, nullptr, bids, gout, nbase, tid);
  } else {
    layer6<128, 512, 1>(actmem, wring, Wa, ba, sh, bids, nullptr, nbase, tid);
    layer6<512, 512, 0>(actmem, wring, Wb, bb, nullptr, bids, nullptr, nbase, tid);
    layer6<512, 512, 0>(actmem, wring, Wc, bc, nullptr, bids, nullptr, nbase, tid);
    layer6<512, 512, 0>(actmem, wring, Wd, bd, nullptr, bids, nullptr, nbase, tid);
    layer6<512, 128, 3>(actmem, wring, We, be, nullptr, bids, gout, nbase, tid);
  }
}

extern "C" void kernel_launch(void* const* d_in, const int* in_sizes, int n_in,
                              void* d_out, int out_size, void* d_ws, size_t ws_size,
                              hipStream_t stream) {
  const float* x      = (const float*)d_in[0];
  const int*   bids   = (const int*)  d_in[1];
  const float* ge_W0  = (const float*)d_in[2];
  const float* ge_b0  = (const float*)d_in[3];
  const float* ge_Wh  = (const float*)d_in[4];
  const float* ge_bh  = (const float*)d_in[5];
  const float* ge_Wo  = (const float*)d_in[6];
  const float* ge_bo  = (const float*)d_in[7];
  const float* in_W   = (const float*)d_in[8];
  const float* in_b   = (const float*)d_in[9];
  const float* ag_W   = (const float*)d_in[10];
  const float* ag_b   = (const float*)d_in[11];
  const float* psi_Wh = (const float*)d_in[12];
  const float* psi_bh = (const float*)d_in[13];
  const float* psi_Wo = (const float*)d_in[14];
  const float* psi_bo = (const float*)d_in[15];

  char* ws = (char*)d_ws;
  __hip_bfloat16* geW0C   = (__hip_bfloat16*)(ws + 0);        // slab [16][512]
  __hip_bfloat16* geWh0C  = (__hip_bfloat16*)(ws + 131072);   // [64][512]
  __hip_bfloat16* geWh1C  = (__hip_bfloat16*)(ws + 655360);
  __hip_bfloat16* geWoC   = (__hip_bfloat16*)(ws + 1179648);  // [64][256]
  __hip_bfloat16* inWC    = (__hip_bfloat16*)(ws + 1441792);  // [16][512]
  __hip_bfloat16* agWT    = (__hip_bfloat16*)(ws + 1572864);  // OLD layout [512][256]
  __hip_bfloat16* psiWh0C = (__hip_bfloat16*)(ws + 1835008);
  __hip_bfloat16* psiWh1C = (__hip_bfloat16*)(ws + 2359296);
  __hip_bfloat16* psiWh2C = (__hip_bfloat16*)(ws + 2883584);
  __hip_bfloat16* psiWoC  = (__hip_bfloat16*)(ws + 3407872);  // [64][128]
  __hip_bfloat16* sigma   = (__hip_bfloat16*)(ws + 3538944);  // [1024][256] bf16
  float*          sh      = (float*)         (ws + 4063232);  // [1024][512] f32
  float*          sums    = (float*)         (ws + 6160384);  // [1024][256] f32

  if (ws_size < 7340032) {
    sentinel<<<1, 64, 0, stream>>>((float*)d_out, 100000000.f + (float)(ws_size / 1024));
    return;
  }

  dim3 blk(256);
  hipMemsetAsync(sums, 0, NUM_G * 256 * sizeof(float), stream);

  // ---- weight conversions ----
  wt_convC<9><<<256,  blk, 0, stream>>>(ge_W0,           geW0C);
  wt_convC<9><<<1024, blk, 0, stream>>>(ge_Wh,           geWh0C);
  wt_convC<9><<<1024, blk, 0, stream>>>(ge_Wh + 262144,  geWh1C);
  wt_convC<8><<<512,  blk, 0, stream>>>(ge_Wo,           geWoC);
  wt_convC<9><<<256,  blk, 0, stream>>>(in_W,            inWC);
  wt_conv<<<dim3(16, 8), blk, 0, stream>>>(ag_W, agWT, 256, 512);   // old layout
  wt_convC<9><<<1024, blk, 0, stream>>>(psi_Wh,          psiWh0C);
  wt_convC<9><<<1024, blk, 0, stream>>>(psi_Wh + 262144, psiWh1C);
  wt_convC<9><<<1024, blk, 0, stream>>>(psi_Wh + 524288, psiWh2C);
  wt_convC<7><<<256,  blk, 0, stream>>>(psi_Wo,          psiWoC);

  // ---- ge chain fused (writes segment sums) ----
  fused_chain6<0><<<N_NODES / 128, 512, 0, stream>>>(
      x, bids, geW0C, ge_b0, geWh0C, ge_bh, geWh1C, ge_bh + 512, geWoC, ge_bo,
      nullptr, nullptr, nullptr, sums);

  // ---- sigma; sh = sigma @ agWT + agb ----
  sigma_fin<<<NUM_G, blk, 0, stream>>>(sums, bids, sigma);
  gemm_mfma<0, 0><<<dim3(4, 8), blk, 0, stream>>>(sigma, agWT, ag_b, sh, 256, 512);

  // ---- psi chain fused (writes d_out) ----
  fused_chain6<1><<<N_NODES / 128, 512, 0, stream>>>(
      x, bids, inWC, in_b, psiWh0C, psi_bh, psiWh1C, psi_bh + 512,
      psiWh2C, psi_bh + 1024, psiWoC, psi_bo, sh, (float*)d_out);
}